// Round 14
// baseline (651.208 us; speedup 1.0000x reference)
//
#include <hip/hip_runtime.h>
#include <math.h>

#define NN    50000
#define DD    64
#define HH    4
#define E_RES 400000
#define E_SEQ 100000
#define E_KNN 400000
#define ETOT  (E_RES+E_SEQ+E_KNN)
#define SCH   4096
#define SNB   ((NN + SCH - 1)/SCH)   // 13 chunks per relation
#define RPS   (NN + 4)               // rowptr stride (16B-aligned per relation)
#define NBLK  ((NN+255)/256)         // 196
#define KTOT  832                    // fused matmul K: 64 (x) + 768 (z) = 26*32
#define NG    (NN/16)                // 3125 row-groups (exact)
#define GSZ   13312                  // shorts per group in Zsw: 26 kb * 512

// wbuf byte layout:
//   [0, 106496)        Wfused bf16 [col][j], col stride KTOT
//   [110592, 110848)   biasfused f32[64]
//   [110848 + r*2080)  per relation: Wel f32[512] + biasE f32[8]
//   [117088, 117856)   SrFc f32[3][64]  (deg-flag correction, post-fc)

typedef __attribute__((ext_vector_type(8))) short short8;
typedef __attribute__((ext_vector_type(4))) float floatx4;

__device__ inline unsigned short f2bf(float f){
  union{float f; unsigned u;} v; v.f=f;
  unsigned r = v.u + 0x7FFF + ((v.u>>16)&1);
  return (unsigned short)(r>>16);
}
__device__ inline float bf2f(unsigned short u){
  union{unsigned u; float f;} v; v.u=(unsigned)u<<16; return v.f;
}

// ---------------- CSR build (merged over 3 relations) -----------------------
__global__ void k_hist3(const int* __restrict__ d0, const int* __restrict__ d1,
                        const int* __restrict__ d2, int* __restrict__ cnt){
  int i = blockIdx.x*256 + threadIdx.x;
  if(i < E_RES)                atomicAdd(&cnt[d0[i]], 1);
  else if(i < E_RES+E_SEQ)     atomicAdd(&cnt[NN + d1[i-E_RES]], 1);
  else if(i < ETOT)            atomicAdd(&cnt[2*NN + d2[i-E_RES-E_SEQ]], 1);
}

__global__ void __launch_bounds__(256)
k_blocksum(const int* __restrict__ hist, int* __restrict__ bsums){
  int r = blockIdx.x / SNB, b = blockIdx.x % SNB;
  const int* cnt = hist + r*NN;
  int t = threadIdx.x;
  int end = min((b+1)*SCH, NN);
  int s = 0;
  for(int j = b*SCH + t; j < end; j += 256) s += cnt[j];
  __shared__ int sh[4];
  for(int off=32; off; off>>=1) s += __shfl_down(s, off, 64);
  int lane = t & 63, w = t >> 6;
  if(lane==0) sh[w]=s;
  __syncthreads();
  if(t==0) bsums[blockIdx.x] = sh[0]+sh[1]+sh[2]+sh[3];
}

__global__ void __launch_bounds__(256)
k_scanwrite(const int* __restrict__ hist, const int* __restrict__ bsums,
            int* __restrict__ rowptr, int* __restrict__ cursor){
  int r = blockIdx.x / SNB, b = blockIdx.x % SNB;
  const int* cnt = hist + r*NN;
  int* rp  = rowptr + r*RPS;
  int* cur = cursor + r*NN;
  __shared__ int sh_off;
  __shared__ int wtot[4];
  int t = threadIdx.x;
  if(t==0){
    int o=0, tot=0;
    for(int i=0;i<SNB;i++){ int v=bsums[r*SNB+i]; if(i<b) o+=v; tot+=v; }
    sh_off=o;
    if(b==0) rp[NN]=tot;
  }
  int base = b*SCH + t*16;
  int v[16];
  bool full = (base+16 <= NN);
  if(full){
    int4 a0=((const int4*)cnt)[base/4+0];
    int4 a1=((const int4*)cnt)[base/4+1];
    int4 a2=((const int4*)cnt)[base/4+2];
    int4 a3=((const int4*)cnt)[base/4+3];
    v[0]=a0.x;v[1]=a0.y;v[2]=a0.z;v[3]=a0.w;
    v[4]=a1.x;v[5]=a1.y;v[6]=a1.z;v[7]=a1.w;
    v[8]=a2.x;v[9]=a2.y;v[10]=a2.z;v[11]=a2.w;
    v[12]=a3.x;v[13]=a3.y;v[14]=a3.z;v[15]=a3.w;
  } else {
    for(int j=0;j<16;j++){ int idx=base+j; v[j]=(idx<NN)?cnt[idx]:0; }
  }
  int loc=0;
  #pragma unroll
  for(int j=0;j<16;j++) loc += v[j];
  int lane = t & 63, w = t >> 6;
  int inc = loc;
  for(int off=1; off<64; off<<=1){ int n=__shfl_up(inc, off, 64); if(lane>=off) inc+=n; }
  if(lane==63) wtot[w]=inc;
  __syncthreads();
  int woff=0;
  for(int i=0;i<w;i++) woff += wtot[i];
  int run = sh_off + woff + inc - loc;
  if(full){
    int o[16];
    #pragma unroll
    for(int j=0;j<16;j++){ o[j]=run; run+=v[j]; }
    ((int4*)rp )[base/4+0]=make_int4(o[0],o[1],o[2],o[3]);
    ((int4*)rp )[base/4+1]=make_int4(o[4],o[5],o[6],o[7]);
    ((int4*)rp )[base/4+2]=make_int4(o[8],o[9],o[10],o[11]);
    ((int4*)rp )[base/4+3]=make_int4(o[12],o[13],o[14],o[15]);
    ((int4*)cur)[base/4+0]=make_int4(o[0],o[1],o[2],o[3]);
    ((int4*)cur)[base/4+1]=make_int4(o[4],o[5],o[6],o[7]);
    ((int4*)cur)[base/4+2]=make_int4(o[8],o[9],o[10],o[11]);
    ((int4*)cur)[base/4+3]=make_int4(o[12],o[13],o[14],o[15]);
  } else {
    for(int j=0;j<16;j++){
      int idx=base+j;
      if(idx<NN){ rp[idx]=run; cur[idx]=run; run+=v[j]; }
    }
  }
}

__global__ void k_scatter3(const int* __restrict__ s0, const int* __restrict__ d0,
                           const int* __restrict__ s1, const int* __restrict__ d1,
                           const int* __restrict__ s2, const int* __restrict__ d2,
                           int* __restrict__ cursor, int* __restrict__ csr){
  int i = blockIdx.x*256 + threadIdx.x;
  if(i < E_RES){
    int pos = atomicAdd(&cursor[d0[i]],1); csr[pos]=s0[i];
  } else if(i < E_RES+E_SEQ){
    int j=i-E_RES;
    int pos = atomicAdd(&cursor[NN+d1[j]],1); csr[E_RES+pos]=s1[j];
  } else if(i < ETOT){
    int j=i-E_RES-E_SEQ;
    int pos = atomicAdd(&cursor[2*NN+d2[j]],1); csr[E_RES+E_SEQ+pos]=s2[j];
  }
}

// ---------------- BN stats + bf16 cast (layer 1 input) ----------------------
__global__ void k_bnstats(const float* __restrict__ x, float* __restrict__ stats,
                          unsigned short* __restrict__ Abf){
  __shared__ float sh[512];
  int t = threadIdx.x, col = t & 63, rg = t >> 6;
  float s=0.f, q=0.f;
  for(int row = blockIdx.x*4 + rg; row < NN; row += gridDim.x*4){
    float v = x[(size_t)row*64 + col]; s += v; q += v*v;
    Abf[(size_t)row*64 + col] = f2bf(v);
  }
  sh[t]=s; sh[256+t]=q; __syncthreads();
  if(rg==0){
    s = sh[col]+sh[64+col]+sh[128+col]+sh[192+col];
    q = sh[256+col]+sh[320+col]+sh[384+col]+sh[448+col];
    atomicAdd(&stats[col], s); atomicAdd(&stats[64+col], q);
  }
}

// ---------------- prep: build fused weights ---------------------------------
__global__ void __launch_bounds__(256)
k_prep3(const float* __restrict__ stats, const float* __restrict__ g,
        const float* __restrict__ be, const float* __restrict__ W,
        const float* __restrict__ al, const float* __restrict__ ar,
        const float* __restrict__ b, const float* __restrict__ rW,
        const float* __restrict__ fcW, const float* __restrict__ fcb,
        float* __restrict__ wbufF){
  __shared__ float scale[64], shift[64];
  int t = threadIdx.x;
  if(t<64){
    float mu  = stats[t]*(1.0f/NN);
    float var = stats[64+t]*(1.0f/NN) - mu*mu;
    float sc  = g[t]*rsqrtf(var + 1e-5f);
    scale[t]=sc; shift[t]=be[t]-mu*sc;
  }
  __syncthreads();
  char* wb = (char*)wbufF;
  unsigned short* Wf = (unsigned short*)wbufF;
  float* biasF = (float*)(wb + 110592);
  float* SrFc  = (float*)(wb + 117088);
  int bid = blockIdx.x;
  if(bid < 52){
    __shared__ float fcWs[4096];
    for(int i=t;i<4096;i+=256) fcWs[i]=fcW[i];
    __syncthreads();
    int j = bid*16 + (t>>4);          // 0..831 exactly
    int cg = (t&15)*4;
    float Wrow[64];
    if(j < 64){
      for(int d=0; d<64; d++){
        float w=0.f;
        for(int r=0;r<3;r++)
          #pragma unroll
          for(int h=0;h<4;h++)
            w += rW[((size_t)(r*64+j))*256 + h*64 + d];
        Wrow[d] = scale[j]*0.25f*w;
      }
    } else {
      int jj = j-64;
      int r = jj>>8, hc = jj&255, h = hc>>6, c = hc&63;
      const float* Wp = W + ((size_t)(r*64+c))*256 + h*64;
      float sc = 0.25f*scale[c];
      #pragma unroll
      for(int d=0; d<64; d++) Wrow[d] = sc*Wp[d];
    }
    #pragma unroll
    for(int cc=0; cc<4; cc++){
      int col = cg+cc;
      float acc=0.f;
      #pragma unroll
      for(int d=0; d<64; d++) acc += Wrow[d]*fcWs[d*64+col];
      Wf[(size_t)col*KTOT + j] = f2bf(acc);
    }
  } else if(bid < 58){
    int wv = (bid-52)*4 + (t>>6);        // 0..23
    int r = wv >> 3, cc = wv & 7, h = cc & 3, k = t & 63;
    const float* av = ((cc>=4)?ar:al) + (r*HH+h)*64;
    const float* Wk = W + ((size_t)(r*64+k))*256 + h*64;
    float w=0.f;
    for(int d2=0; d2<64; d2++) w += Wk[d2]*av[d2];
    float* WelR = (float*)(wb + 110848 + r*2080);
    WelR[cc*64 + k] = scale[k]*w;
    float bp = shift[k]*w;
    for(int off=32; off; off>>=1) bp += __shfl_down(bp, off, 64);
    if(k==0) (WelR + 512)[cc] = bp;
  } else {
    __shared__ float S[3][64];
    __shared__ float BH[64];
    if(t<192){
      int r=t>>6, d=t&63;
      float s=0.f;
      #pragma unroll
      for(int h=0;h<4;h++){
        const float* Wp = W + (size_t)(r*64)*256 + h*64 + d;
        for(int k=0;k<64;k++) s += shift[k]*Wp[(size_t)k*256];
      }
      S[r][d]=0.25f*s;
    } else {
      int d = t-192;
      float s=0.f;
      for(int k=0;k<64;k++){
        float w=0.f;
        for(int r=0;r<3;r++)
          #pragma unroll
          for(int h=0;h<4;h++)
            w += rW[((size_t)(r*64+k))*256 + h*64 + d];
        s += shift[k]*0.25f*w;
      }
      float bb=0.f;
      for(int r=0;r<3;r++)
        #pragma unroll
        for(int h=0;h<4;h++) bb += b[r*256 + h*64 + d];
      BH[d] = s + 0.25f*bb;
    }
    __syncthreads();
    if(t<192){
      int r=t>>6, col=t&63;
      float acc=0.f;
      for(int d=0;d<64;d++) acc += S[r][d]*fcW[d*64+col];
      SrFc[r*64 + col] = acc;            // f32 epilogue correction
    } else {
      int col=t-192;
      float acc=0.f;
      for(int d=0;d<64;d++) acc += BH[d]*fcW[d*64+col];
      biasF[col] = acc + fcb[col];
    }
  }
}

// ---------------- el/er (all 3 relations): EL[r][N,8] -----------------------
// use16: read A16 (bf16) instead of A32 (f32).
__global__ void __launch_bounds__(256)
k_el3(const float* __restrict__ A32, const unsigned short* __restrict__ A16,
      int use16, const float* __restrict__ wbufF, float* __restrict__ EL){
  int r = blockIdx.x / NBLK;
  const char* wb = (const char*)wbufF;
  const float* Wel = (const float*)(wb + 110848 + r*2080);
  const float* biasE = Wel + 512;
  float* ELr = EL + (size_t)r*NN*8;
  __shared__ float sw[512];
  __shared__ float sb[8];
  int t = threadIdx.x;
  sw[t]=Wel[t]; sw[256+t]=Wel[256+t];
  if(t<8) sb[t]=biasE[t];
  __syncthreads();
  int n = (blockIdx.x % NBLK)*256 + t;
  if(n>=NN) return;
  float acc[8];
  #pragma unroll
  for(int c=0;c<8;c++) acc[c]=sb[c];
  #pragma unroll
  for(int kq=0;kq<16;kq++){
    float ax,ay,az,aw;
    if(use16){
      ushort4 a4 = ((const ushort4*)(A16 + (size_t)n*64))[kq];
      ax=bf2f(a4.x); ay=bf2f(a4.y); az=bf2f(a4.z); aw=bf2f(a4.w);
    } else {
      float4 a4 = ((const float4*)(A32 + (size_t)n*64))[kq];
      ax=a4.x; ay=a4.y; az=a4.z; aw=a4.w;
    }
    #pragma unroll
    for(int c=0;c<8;c++){
      const float* w = sw + c*64 + kq*4;
      acc[c] += ax*w[0] + ay*w[1] + az*w[2] + aw*w[3];
    }
  }
  ((float4*)ELr)[n*2]   = make_float4(acc[0],acc[1],acc[2],acc[3]);
  ((float4*)ELr)[n*2+1] = make_float4(acc[4],acc[5],acc[6],acc[7]);
}

// ---------------- edge coefficients: pass2 recompute, write f32 alpha -------
__global__ void __launch_bounds__(256)
k_edgecoef3(const float* __restrict__ EL, const int* __restrict__ rowptr,
            const int* __restrict__ csr, float4* __restrict__ coef){
  int r = blockIdx.x / NBLK;
  const float* ELr = EL + (size_t)r*NN*8;
  const int* rp = rowptr + r*RPS;
  int off = (r==0)?0:(r==1)?E_RES:(E_RES+E_SEQ);
  const int* cs = csr + off;
  float4* cf = coef + off;
  int n = (blockIdx.x % NBLK)*256 + threadIdx.x;
  if(n>=NN) return;
  int beg = rp[n], end = rp[n+1];
  if(end<=beg) return;
  const float4 er = ((const float4*)ELr)[n*2+1];
  float m0=-1e30f,m1=-1e30f,m2=-1e30f,m3=-1e30f;
  float s0=0.f,s1=0.f,s2=0.f,s3=0.f;
  for(int i=beg;i<end;i++){
    int src = cs[i];
    float4 el = ((const float4*)ELr)[src*2];
    float e0=el.x+er.x, e1=el.y+er.y, e2=el.z+er.z, e3=el.w+er.w;
    e0 = e0>0.f? e0 : 0.2f*e0;
    e1 = e1>0.f? e1 : 0.2f*e1;
    e2 = e2>0.f? e2 : 0.2f*e2;
    e3 = e3>0.f? e3 : 0.2f*e3;
    float n0=fmaxf(m0,e0); s0=s0*__expf(m0-n0)+__expf(e0-n0); m0=n0;
    float n1=fmaxf(m1,e1); s1=s1*__expf(m1-n1)+__expf(e1-n1); m1=n1;
    float n2=fmaxf(m2,e2); s2=s2*__expf(m2-n2)+__expf(e2-n2); m2=n2;
    float n3=fmaxf(m3,e3); s3=s3*__expf(m3-n3)+__expf(e3-n3); m3=n3;
  }
  float r0=1.f/s0, r1=1.f/s1, r2=1.f/s2, r3=1.f/s3;
  for(int i=beg;i<end;i++){
    int src = cs[i];
    float4 el = ((const float4*)ELr)[src*2];
    float e0=el.x+er.x, e1=el.y+er.y, e2=el.z+er.z, e3=el.w+er.w;
    e0 = e0>0.f? e0 : 0.2f*e0;
    e1 = e1>0.f? e1 : 0.2f*e1;
    e2 = e2>0.f? e2 : 0.2f*e2;
    e3 = e3>0.f? e3 : 0.2f*e3;
    cf[i] = make_float4(__expf(e0-m0)*r0, __expf(e1-m1)*r1,
                        __expf(e2-m2)*r2, __expf(e3-m3)*r3);
  }
}

// ---------------- z-gather: one WAVE per (node, relation) -------------------
// Writes z directly in MFMA-fragment-swizzled layout:
//   Zsw[g*GSZ + kb*512 + kq*128 + m*8 + j], g=node/16, m=node%16,
//   K(kb,kq,j) = kb*32+kq*8+j; z element K = 64+(r*4+h)*64+d.
// r==0 wave also copies the node's own x row into kb 0..1 slots, and each
// wave writes its relation's deg flag byte.
__global__ void __launch_bounds__(256)
k_aggzr(const unsigned short* __restrict__ Abf, const int* __restrict__ rowptr,
        const int* __restrict__ csr, const float4* __restrict__ coef,
        unsigned short* __restrict__ Zsw, unsigned char* __restrict__ flags){
  int w    = (blockIdx.x*256 + threadIdx.x) >> 6;
  int lane = threadIdx.x & 63;
  int r = w / NN, wid = w - r*NN;
  const int* rp = rowptr + r*RPS;
  int off = (r==0)?0:(r==1)?E_RES:(E_RES+E_SEQ);
  const int* cs = csr + off;
  const float4* cf = coef + off;
  int beg = rp[wid], end = rp[wid+1];
  float z0=0.f,z1=0.f,z2=0.f,z3=0.f;
  int i = beg;
  for(; i+4<=end; i+=4){
    int s0=cs[i], s1=cs[i+1], s2=cs[i+2], s3=cs[i+3];
    float4 c0=cf[i], c1=cf[i+1], c2=cf[i+2], c3=cf[i+3];
    float x0=bf2f(Abf[(size_t)s0*64+lane]);
    float x1=bf2f(Abf[(size_t)s1*64+lane]);
    float x2=bf2f(Abf[(size_t)s2*64+lane]);
    float x3=bf2f(Abf[(size_t)s3*64+lane]);
    z0 += c0.x*x0 + c1.x*x1 + c2.x*x2 + c3.x*x3;
    z1 += c0.y*x0 + c1.y*x1 + c2.y*x2 + c3.y*x3;
    z2 += c0.z*x0 + c1.z*x1 + c2.z*x2 + c3.z*x3;
    z3 += c0.w*x0 + c1.w*x1 + c2.w*x2 + c3.w*x3;
  }
  for(; i<end; i++){
    int s=cs[i];
    float4 c=cf[i];
    float x=bf2f(Abf[(size_t)s*64+lane]);
    z0 += c.x*x; z1 += c.y*x; z2 += c.z*x; z3 += c.w*x;
  }
  int g = wid>>4, mm = wid&15;
  size_t zb = (size_t)g*GSZ + ((lane>>3)&3)*128 + mm*8 + (lane&7);
  int kb0 = 2 + r*8 + (lane>>5);
  Zsw[zb + (size_t)(kb0+0)*512] = f2bf(z0);
  Zsw[zb + (size_t)(kb0+2)*512] = f2bf(z1);
  Zsw[zb + (size_t)(kb0+4)*512] = f2bf(z2);
  Zsw[zb + (size_t)(kb0+6)*512] = f2bf(z3);
  if(r==0)
    Zsw[zb + (size_t)(lane>>5)*512] = Abf[(size_t)wid*64 + lane];
  if(lane==0) flags[r*NN+wid] = (end>beg)?1:0;
}

// ---------------- fused MFMA (swizzled A): out = relu([x|z]@Wf + bias + corr)
// 4 waves/block; wave wv owns row-group g = blockIdx*4+wv (16 rows), all 64 cols.
// layer1: write bf16 Abf2 + BN stats; else write f32 out.
__global__ void __launch_bounds__(256)
k_mfmaZs(const unsigned short* __restrict__ Zsw, const float* __restrict__ wbufF,
         const unsigned char* __restrict__ flags, float* __restrict__ out,
         unsigned short* __restrict__ Abf2, float* __restrict__ stats, int layer1){
  __shared__ float spart[4][2][64];
  const char* wb = (const char*)wbufF;
  const unsigned short* Wf = (const unsigned short*)wbufF;
  const float* biasF = (const float*)(wb + 110592);
  const float* SrFc  = (const float*)(wb + 117088);
  int t = threadIdx.x, wv = t>>6, lane = t&63, m = lane&15, kq = lane>>4;
  int g = blockIdx.x*4 + wv;
  bool valid = (g < NG);
  int gc = valid ? g : NG-1;
  const unsigned short* Zg = Zsw + (size_t)gc*GSZ;
  floatx4 acc0 = {0.f,0.f,0.f,0.f};
  floatx4 acc1 = {0.f,0.f,0.f,0.f};
  floatx4 acc2 = {0.f,0.f,0.f,0.f};
  floatx4 acc3 = {0.f,0.f,0.f,0.f};
  #pragma unroll
  for(int kb=0; kb<26; kb++){
    short8 a = *(const short8*)(Zg + kb*512 + lane*8);   // fully coalesced
    int ko = kb*32 + kq*8;
    short8 b0 = *(const short8*)(Wf + (size_t)(0*16+m)*KTOT + ko);
    short8 b1 = *(const short8*)(Wf + (size_t)(1*16+m)*KTOT + ko);
    short8 b2 = *(const short8*)(Wf + (size_t)(2*16+m)*KTOT + ko);
    short8 b3 = *(const short8*)(Wf + (size_t)(3*16+m)*KTOT + ko);
    acc0 = __builtin_amdgcn_mfma_f32_16x16x32_bf16(a, b0, acc0, 0,0,0);
    acc1 = __builtin_amdgcn_mfma_f32_16x16x32_bf16(a, b1, acc1, 0,0,0);
    acc2 = __builtin_amdgcn_mfma_f32_16x16x32_bf16(a, b2, acc2, 0,0,0);
    acc3 = __builtin_amdgcn_mfma_f32_16x16x32_bf16(a, b3, acc3, 0,0,0);
  }
  #pragma unroll
  for(int ct=0; ct<4; ct++){
    int col = ct*16 + m;
    floatx4 acc = (ct==0)?acc0:(ct==1)?acc1:(ct==2)?acc2:acc3;
    float bb = biasF[col];
    float c0 = SrFc[col], c1 = SrFc[64+col], c2 = SrFc[128+col];
    float sv=0.f, qv=0.f;
    #pragma unroll
    for(int ri=0; ri<4; ri++){
      if(valid){
        int ro = g*16 + kq*4 + ri;
        float corr = (flags[ro]      ? c0:0.f)
                   + (flags[NN+ro]   ? c1:0.f)
                   + (flags[2*NN+ro] ? c2:0.f);
        float v = fmaxf(acc[ri] + bb + corr, 0.f);
        if(layer1){
          Abf2[(size_t)ro*64 + col] = f2bf(v);
          sv += v; qv += v*v;
        } else {
          out[(size_t)ro*64 + col] = v;
        }
      }
    }
    if(layer1){
      sv += __shfl_xor(sv, 16, 64); qv += __shfl_xor(qv, 16, 64);
      sv += __shfl_xor(sv, 32, 64); qv += __shfl_xor(qv, 32, 64);
      if(kq==0){ spart[wv][0][col]=sv; spart[wv][1][col]=qv; }
    }
  }
  if(layer1){
    __syncthreads();
    if(t<64){
      float s = spart[0][0][t]+spart[1][0][t]+spart[2][0][t]+spart[3][0][t];
      float q = spart[0][1][t]+spart[1][1][t]+spart[2][1][t]+spart[3][1][t];
      atomicAdd(&stats[t], s); atomicAdd(&stats[64+t], q);
    }
  }
}

extern "C" void kernel_launch(void* const* d_in, const int* in_sizes, int n_in,
                              void* d_out, int out_size, void* d_ws, size_t ws_size,
                              hipStream_t stream){
  const float* x      =(const float*)d_in[0];
  const int* src_res  =(const int*)d_in[1];
  const int* dst_res  =(const int*)d_in[2];
  const int* src_seq  =(const int*)d_in[3];
  const int* dst_seq  =(const int*)d_in[4];
  const int* src_knn  =(const int*)d_in[5];
  const int* dst_knn  =(const int*)d_in[6];
  const float* W0 =(const float*)d_in[7];
  const float* al0=(const float*)d_in[8];
  const float* ar0=(const float*)d_in[9];
  const float* b0 =(const float*)d_in[10];
  const float* rW0=(const float*)d_in[11];
  const float* W1 =(const float*)d_in[12];
  const float* al1=(const float*)d_in[13];
  const float* ar1=(const float*)d_in[14];
  const float* b1 =(const float*)d_in[15];
  const float* rW1=(const float*)d_in[16];
  const float* fcW0=(const float*)d_in[17];
  const float* fcb0=(const float*)d_in[18];
  const float* fcW1=(const float*)d_in[19];
  const float* fcb1=(const float*)d_in[20];
  const float* g0 =(const float*)d_in[21];
  const float* be0=(const float*)d_in[22];
  const float* g1 =(const float*)d_in[23];
  const float* be1=(const float*)d_in[24];

  char* ws=(char*)d_ws;
  int*   hist   =(int*)  (ws+0);               // 3*NN ints
  float* stats0 =(float*)(ws+600000);
  float* stats1 =(float*)(ws+600512);
  int*   rowptr =(int*)  (ws+601024);          // 3*RPS ints
  int*   cursor =(int*)  (ws+1201088);
  int*   csr    =(int*)  (ws+1801088);         // 900000 ints
  float* wbuf   =(float*)(ws+5401088);         // ~118 KB
  int*   bsums  =(int*)  (ws+5525344);         // 39 ints
  unsigned short* Abf  =(unsigned short*)(ws+5526528);   // NN*64 bf16 = 6.4MB
  unsigned short* Zsw  =(unsigned short*)(ws+11926528UL);// NG*GSZ bf16 = 83.2MB
  unsigned char* flags =(unsigned char*)(ws+104426528UL);// 3*NN bytes
  float* EL     =(float*)(ws+104726528UL);     // 3*NN*8 f32
  float4* coef  =(float4*)(ws+109526528UL);    // 900000 float4 = 14.4MB
  unsigned short* Abf2 =(unsigned short*)(ws+123926528UL); // NN*64 bf16 (layer-2 A)

  hipMemsetAsync(ws, 0, 601024, stream);  // hist + both stats buffers

  const int EBLK=(ETOT+255)/256;   // 3516
  k_hist3<<<EBLK,256,0,stream>>>(dst_res,dst_seq,dst_knn,hist);
  k_blocksum<<<3*SNB,256,0,stream>>>(hist,bsums);
  k_scanwrite<<<3*SNB,256,0,stream>>>(hist,bsums,rowptr,cursor);
  k_scatter3<<<EBLK,256,0,stream>>>(src_res,dst_res,src_seq,dst_seq,
                                    src_knn,dst_knn,cursor,csr);

  const int ZBLK=(3*NN*64)/256;  // 37500 (exact)
  const int MB4 =(NG+3)/4;       // 782 blocks, 4 row-groups each
  // ---- layer 1 ----
  k_bnstats<<<256,256,0,stream>>>(x,stats0,Abf);
  k_prep3<<<59,256,0,stream>>>(stats0,g0,be0,W0,al0,ar0,b0,rW0,fcW0,fcb0,wbuf);
  k_el3<<<3*NBLK,256,0,stream>>>(x,Abf,0,wbuf,EL);
  k_edgecoef3<<<3*NBLK,256,0,stream>>>(EL,rowptr,csr,coef);
  k_aggzr<<<ZBLK,256,0,stream>>>(Abf,rowptr,csr,coef,Zsw,flags);
  k_mfmaZs<<<MB4,256,0,stream>>>(Zsw,wbuf,flags,(float*)d_out,Abf2,stats1,1);
  // ---- layer 2 ----
  k_prep3<<<59,256,0,stream>>>(stats1,g1,be1,W1,al1,ar1,b1,rW1,fcW1,fcb1,wbuf);
  k_el3<<<3*NBLK,256,0,stream>>>(x,Abf2,1,wbuf,EL);
  k_edgecoef3<<<3*NBLK,256,0,stream>>>(EL,rowptr,csr,coef);
  k_aggzr<<<ZBLK,256,0,stream>>>(Abf2,rowptr,csr,coef,Zsw,flags);
  k_mfmaZs<<<MB4,256,0,stream>>>(Zsw,wbuf,flags,(float*)d_out,Abf2,stats0,0);
}

// Round 15
// 537.784 us; speedup vs baseline: 1.2109x; 1.2109x over previous
//
#include <hip/hip_runtime.h>
#include <math.h>

#define NN    50000
#define DD    64
#define HH    4
#define E_RES 400000
#define E_SEQ 100000
#define E_KNN 400000
#define ETOT  (E_RES+E_SEQ+E_KNN)
#define SCH   4096
#define SNB   ((NN + SCH - 1)/SCH)   // 13 chunks per relation
#define RPS   (NN + 4)               // rowptr stride (16B-aligned per relation)
#define MBLK  ((NN+63)/64)           // 782
#define NBLK  ((NN+255)/256)         // 196
#define ZS    800                    // Z stride (shorts): 768 z + 3 flags + 29 pad
#define KTOT  864                    // fused matmul K: 64 (x) + 800 (z+flags+pad)

typedef __attribute__((ext_vector_type(8))) short short8;
typedef __attribute__((ext_vector_type(4))) float floatx4;

__device__ inline unsigned short f2bf(float f){
  union{float f; unsigned u;} v; v.f=f;
  unsigned r = v.u + 0x7FFF + ((v.u>>16)&1);
  return (unsigned short)(r>>16);
}
__device__ inline float bf2f(unsigned short u){
  union{unsigned u; float f;} v; v.u=(unsigned)u<<16; return v.f;
}

// ---------------- CSR build (merged over 3 relations) -----------------------
__global__ void k_hist3(const int* __restrict__ d0, const int* __restrict__ d1,
                        const int* __restrict__ d2, int* __restrict__ cnt){
  int i = blockIdx.x*256 + threadIdx.x;
  if(i < E_RES)                atomicAdd(&cnt[d0[i]], 1);
  else if(i < E_RES+E_SEQ)     atomicAdd(&cnt[NN + d1[i-E_RES]], 1);
  else if(i < ETOT)            atomicAdd(&cnt[2*NN + d2[i-E_RES-E_SEQ]], 1);
}

__global__ void __launch_bounds__(256)
k_blocksum(const int* __restrict__ hist, int* __restrict__ bsums){
  int r = blockIdx.x / SNB, b = blockIdx.x % SNB;
  const int* cnt = hist + r*NN;
  int t = threadIdx.x;
  int end = min((b+1)*SCH, NN);
  int s = 0;
  for(int j = b*SCH + t; j < end; j += 256) s += cnt[j];
  __shared__ int sh[4];
  for(int off=32; off; off>>=1) s += __shfl_down(s, off, 64);
  int lane = t & 63, w = t >> 6;
  if(lane==0) sh[w]=s;
  __syncthreads();
  if(t==0) bsums[blockIdx.x] = sh[0]+sh[1]+sh[2]+sh[3];
}

__global__ void __launch_bounds__(256)
k_scanwrite(const int* __restrict__ hist, const int* __restrict__ bsums,
            int* __restrict__ rowptr, int* __restrict__ cursor){
  int r = blockIdx.x / SNB, b = blockIdx.x % SNB;
  const int* cnt = hist + r*NN;
  int* rp  = rowptr + r*RPS;
  int* cur = cursor + r*NN;
  __shared__ int sh_off;
  __shared__ int wtot[4];
  int t = threadIdx.x;
  if(t==0){
    int o=0, tot=0;
    for(int i=0;i<SNB;i++){ int v=bsums[r*SNB+i]; if(i<b) o+=v; tot+=v; }
    sh_off=o;
    if(b==0) rp[NN]=tot;
  }
  int base = b*SCH + t*16;
  int v[16];
  bool full = (base+16 <= NN);
  if(full){
    int4 a0=((const int4*)cnt)[base/4+0];
    int4 a1=((const int4*)cnt)[base/4+1];
    int4 a2=((const int4*)cnt)[base/4+2];
    int4 a3=((const int4*)cnt)[base/4+3];
    v[0]=a0.x;v[1]=a0.y;v[2]=a0.z;v[3]=a0.w;
    v[4]=a1.x;v[5]=a1.y;v[6]=a1.z;v[7]=a1.w;
    v[8]=a2.x;v[9]=a2.y;v[10]=a2.z;v[11]=a2.w;
    v[12]=a3.x;v[13]=a3.y;v[14]=a3.z;v[15]=a3.w;
  } else {
    for(int j=0;j<16;j++){ int idx=base+j; v[j]=(idx<NN)?cnt[idx]:0; }
  }
  int loc=0;
  #pragma unroll
  for(int j=0;j<16;j++) loc += v[j];
  int lane = t & 63, w = t >> 6;
  int inc = loc;
  for(int off=1; off<64; off<<=1){ int n=__shfl_up(inc, off, 64); if(lane>=off) inc+=n; }
  if(lane==63) wtot[w]=inc;
  __syncthreads();
  int woff=0;
  for(int i=0;i<w;i++) woff += wtot[i];
  int run = sh_off + woff + inc - loc;
  if(full){
    int o[16];
    #pragma unroll
    for(int j=0;j<16;j++){ o[j]=run; run+=v[j]; }
    ((int4*)rp )[base/4+0]=make_int4(o[0],o[1],o[2],o[3]);
    ((int4*)rp )[base/4+1]=make_int4(o[4],o[5],o[6],o[7]);
    ((int4*)rp )[base/4+2]=make_int4(o[8],o[9],o[10],o[11]);
    ((int4*)rp )[base/4+3]=make_int4(o[12],o[13],o[14],o[15]);
    ((int4*)cur)[base/4+0]=make_int4(o[0],o[1],o[2],o[3]);
    ((int4*)cur)[base/4+1]=make_int4(o[4],o[5],o[6],o[7]);
    ((int4*)cur)[base/4+2]=make_int4(o[8],o[9],o[10],o[11]);
    ((int4*)cur)[base/4+3]=make_int4(o[12],o[13],o[14],o[15]);
  } else {
    for(int j=0;j<16;j++){
      int idx=base+j;
      if(idx<NN){ rp[idx]=run; cur[idx]=run; run+=v[j]; }
    }
  }
}

__global__ void k_scatter3(const int* __restrict__ s0, const int* __restrict__ d0,
                           const int* __restrict__ s1, const int* __restrict__ d1,
                           const int* __restrict__ s2, const int* __restrict__ d2,
                           int* __restrict__ cursor, int* __restrict__ csr){
  int i = blockIdx.x*256 + threadIdx.x;
  if(i < E_RES){
    int pos = atomicAdd(&cursor[d0[i]],1); csr[pos]=s0[i];
  } else if(i < E_RES+E_SEQ){
    int j=i-E_RES;
    int pos = atomicAdd(&cursor[NN+d1[j]],1); csr[E_RES+pos]=s1[j];
  } else if(i < ETOT){
    int j=i-E_RES-E_SEQ;
    int pos = atomicAdd(&cursor[2*NN+d2[j]],1); csr[E_RES+E_SEQ+pos]=s2[j];
  }
}

// ---------------- BN stats + bf16 cast (layer 1 input) ----------------------
__global__ void k_bnstats(const float* __restrict__ x, float* __restrict__ stats,
                          unsigned short* __restrict__ Abf){
  __shared__ float sh[512];
  int t = threadIdx.x, col = t & 63, rg = t >> 6;
  float s=0.f, q=0.f;
  for(int row = blockIdx.x*4 + rg; row < NN; row += gridDim.x*4){
    float v = x[(size_t)row*64 + col]; s += v; q += v*v;
    Abf[(size_t)row*64 + col] = f2bf(v);
  }
  sh[t]=s; sh[256+t]=q; __syncthreads();
  if(rg==0){
    s = sh[col]+sh[64+col]+sh[128+col]+sh[192+col];
    q = sh[256+col]+sh[320+col]+sh[384+col]+sh[448+col];
    atomicAdd(&stats[col], s); atomicAdd(&stats[64+col], q);
  }
}

// ---------------- prep: build fused weights ---------------------------------
__global__ void __launch_bounds__(256)
k_prep3(const float* __restrict__ stats, const float* __restrict__ g,
        const float* __restrict__ be, const float* __restrict__ W,
        const float* __restrict__ al, const float* __restrict__ ar,
        const float* __restrict__ b, const float* __restrict__ rW,
        const float* __restrict__ fcW, const float* __restrict__ fcb,
        float* __restrict__ wbufF){
  __shared__ float scale[64], shift[64];
  int t = threadIdx.x;
  if(t<64){
    float mu  = stats[t]*(1.0f/NN);
    float var = stats[64+t]*(1.0f/NN) - mu*mu;
    float sc  = g[t]*rsqrtf(var + 1e-5f);
    scale[t]=sc; shift[t]=be[t]-mu*sc;
  }
  __syncthreads();
  char* wb = (char*)wbufF;
  unsigned short* Wf = (unsigned short*)wbufF;
  float* biasF = (float*)(wb + 110592);
  int bid = blockIdx.x;
  if(bid < 52){
    __shared__ float fcWs[4096];
    for(int i=t;i<4096;i+=256) fcWs[i]=fcW[i];
    __syncthreads();
    int j = bid*16 + (t>>4);
    int cg = (t&15)*4;
    float Wrow[64];
    if(j < 64){
      for(int d=0; d<64; d++){
        float w=0.f;
        for(int r=0;r<3;r++)
          #pragma unroll
          for(int h=0;h<4;h++)
            w += rW[((size_t)(r*64+j))*256 + h*64 + d];
        Wrow[d] = scale[j]*0.25f*w;
      }
    } else {
      int jj = j-64;
      int r = jj>>8, hc = jj&255, h = hc>>6, c = hc&63;
      const float* Wp = W + ((size_t)(r*64+c))*256 + h*64;
      float sc = 0.25f*scale[c];
      #pragma unroll
      for(int d=0; d<64; d++) Wrow[d] = sc*Wp[d];
    }
    #pragma unroll
    for(int cc=0; cc<4; cc++){
      int col = cg+cc;
      float acc=0.f;
      #pragma unroll
      for(int d=0; d<64; d++) acc += Wrow[d]*fcWs[d*64+col];
      Wf[(size_t)col*KTOT + j] = f2bf(acc);
    }
  } else if(bid < 58){
    int wv = (bid-52)*4 + (t>>6);        // 0..23
    int r = wv >> 3, cc = wv & 7, h = cc & 3, k = t & 63;
    const float* av = ((cc>=4)?ar:al) + (r*HH+h)*64;
    const float* Wk = W + ((size_t)(r*64+k))*256 + h*64;
    float w=0.f;
    for(int d2=0; d2<64; d2++) w += Wk[d2]*av[d2];
    float* WelR = (float*)(wb + 110848 + r*2080);
    WelR[cc*64 + k] = scale[k]*w;
    float bp = shift[k]*w;
    for(int off=32; off; off>>=1) bp += __shfl_down(bp, off, 64);
    if(k==0) (WelR + 512)[cc] = bp;
  } else {
    __shared__ float S[3][64];
    __shared__ float BH[64];
    if(t<192){
      int r=t>>6, d=t&63;
      float s=0.f;
      #pragma unroll
      for(int h=0;h<4;h++){
        const float* Wp = W + (size_t)(r*64)*256 + h*64 + d;
        for(int k=0;k<64;k++) s += shift[k]*Wp[(size_t)k*256];
      }
      S[r][d]=0.25f*s;
    } else {
      int d = t-192;
      float s=0.f;
      for(int k=0;k<64;k++){
        float w=0.f;
        for(int r=0;r<3;r++)
          #pragma unroll
          for(int h=0;h<4;h++)
            w += rW[((size_t)(r*64+k))*256 + h*64 + d];
        s += shift[k]*0.25f*w;
      }
      float bb=0.f;
      for(int r=0;r<3;r++)
        #pragma unroll
        for(int h=0;h<4;h++) bb += b[r*256 + h*64 + d];
      BH[d] = s + 0.25f*bb;
    }
    __syncthreads();
    if(t<192){
      int r=t>>6, col=t&63;
      float acc=0.f;
      for(int d=0;d<64;d++) acc += S[r][d]*fcW[d*64+col];
      Wf[(size_t)col*KTOT + 832 + r] = f2bf(acc);
    } else {
      int col=t-192;
      float acc=0.f;
      for(int d=0;d<64;d++) acc += BH[d]*fcW[d*64+col];
      biasF[col] = acc + fcb[col];
    }
    if(t<64){
      for(int j=835;j<KTOT;j++) Wf[(size_t)t*KTOT + j] = 0;
    }
  }
}

// ---------------- el/er (all 3 relations): EL[r][N,8] -----------------------
__global__ void __launch_bounds__(256)
k_el3(const float* __restrict__ A, const float* __restrict__ wbufF,
      float* __restrict__ EL){
  int r = blockIdx.x / NBLK;
  const char* wb = (const char*)wbufF;
  const float* Wel = (const float*)(wb + 110848 + r*2080);
  const float* biasE = Wel + 512;
  float* ELr = EL + (size_t)r*NN*8;
  __shared__ float sw[512];
  __shared__ float sb[8];
  int t = threadIdx.x;
  sw[t]=Wel[t]; sw[256+t]=Wel[256+t];
  if(t<8) sb[t]=biasE[t];
  __syncthreads();
  int n = (blockIdx.x % NBLK)*256 + t;
  if(n>=NN) return;
  float acc[8];
  #pragma unroll
  for(int c=0;c<8;c++) acc[c]=sb[c];
  const float4* Ar = (const float4*)(A + (size_t)n*64);
  #pragma unroll
  for(int kq=0;kq<16;kq++){
    float4 a = Ar[kq];
    #pragma unroll
    for(int c=0;c<8;c++){
      const float* w = sw + c*64 + kq*4;
      acc[c] += a.x*w[0] + a.y*w[1] + a.z*w[2] + a.w*w[3];
    }
  }
  ((float4*)ELr)[n*2]   = make_float4(acc[0],acc[1],acc[2],acc[3]);
  ((float4*)ELr)[n*2+1] = make_float4(acc[4],acc[5],acc[6],acc[7]);
}

// ---------------- edge coefficients: pass2 recompute, write bf16 alpha ------
__global__ void __launch_bounds__(256)
k_edgecoef3(const float* __restrict__ EL, const int* __restrict__ rowptr,
            const int* __restrict__ csr, ushort4* __restrict__ coefh){
  int r = blockIdx.x / NBLK;
  const float* ELr = EL + (size_t)r*NN*8;
  const int* rp = rowptr + r*RPS;
  int off = (r==0)?0:(r==1)?E_RES:(E_RES+E_SEQ);
  const int* cs = csr + off;
  ushort4* ch = coefh + off;
  int n = (blockIdx.x % NBLK)*256 + threadIdx.x;
  if(n>=NN) return;
  int beg = rp[n], end = rp[n+1];
  if(end<=beg) return;
  const float4 er = ((const float4*)ELr)[n*2+1];
  float m0=-1e30f,m1=-1e30f,m2=-1e30f,m3=-1e30f;
  float s0=0.f,s1=0.f,s2=0.f,s3=0.f;
  for(int i=beg;i<end;i++){
    int src = cs[i];
    float4 el = ((const float4*)ELr)[src*2];
    float e0=el.x+er.x, e1=el.y+er.y, e2=el.z+er.z, e3=el.w+er.w;
    e0 = e0>0.f? e0 : 0.2f*e0;
    e1 = e1>0.f? e1 : 0.2f*e1;
    e2 = e2>0.f? e2 : 0.2f*e2;
    e3 = e3>0.f? e3 : 0.2f*e3;
    float n0=fmaxf(m0,e0); s0=s0*__expf(m0-n0)+__expf(e0-n0); m0=n0;
    float n1=fmaxf(m1,e1); s1=s1*__expf(m1-n1)+__expf(e1-n1); m1=n1;
    float n2=fmaxf(m2,e2); s2=s2*__expf(m2-n2)+__expf(e2-n2); m2=n2;
    float n3=fmaxf(m3,e3); s3=s3*__expf(m3-n3)+__expf(e3-n3); m3=n3;
  }
  float r0=1.f/s0, r1=1.f/s1, r2=1.f/s2, r3=1.f/s3;
  for(int i=beg;i<end;i++){
    int src = cs[i];
    float4 el = ((const float4*)ELr)[src*2];
    float e0=el.x+er.x, e1=el.y+er.y, e2=el.z+er.z, e3=el.w+er.w;
    e0 = e0>0.f? e0 : 0.2f*e0;
    e1 = e1>0.f? e1 : 0.2f*e1;
    e2 = e2>0.f? e2 : 0.2f*e2;
    e3 = e3>0.f? e3 : 0.2f*e3;
    ushort4 o;
    o.x = f2bf(__expf(e0-m0)*r0);
    o.y = f2bf(__expf(e1-m1)*r1);
    o.z = f2bf(__expf(e2-m2)*r2);
    o.w = f2bf(__expf(e3-m3)*r3);
    ch[i] = o;
  }
}

// ---------------- z-gather: one WAVE per (node, relation), bf16 alpha -------
__global__ void __launch_bounds__(256)
k_aggzr(const unsigned short* __restrict__ Abf, const int* __restrict__ rowptr,
        const int* __restrict__ csr, const ushort4* __restrict__ coefh,
        unsigned short* __restrict__ Zbf){
  int w    = (blockIdx.x*256 + threadIdx.x) >> 6;
  int lane = threadIdx.x & 63;
  int r = w / NN, wid = w - r*NN;
  const int* rp = rowptr + r*RPS;
  int off = (r==0)?0:(r==1)?E_RES:(E_RES+E_SEQ);
  const int* cs = csr + off;
  const ushort4* ch = coefh + off;
  int beg = rp[wid], end = rp[wid+1];
  float z0=0.f,z1=0.f,z2=0.f,z3=0.f;
  int i = beg;
  for(; i+4<=end; i+=4){
    int s0=cs[i], s1=cs[i+1], s2=cs[i+2], s3=cs[i+3];
    ushort4 h0=ch[i], h1=ch[i+1], h2=ch[i+2], h3=ch[i+3];
    float x0=bf2f(Abf[(size_t)s0*64+lane]);
    float x1=bf2f(Abf[(size_t)s1*64+lane]);
    float x2=bf2f(Abf[(size_t)s2*64+lane]);
    float x3=bf2f(Abf[(size_t)s3*64+lane]);
    z0 += bf2f(h0.x)*x0 + bf2f(h1.x)*x1 + bf2f(h2.x)*x2 + bf2f(h3.x)*x3;
    z1 += bf2f(h0.y)*x0 + bf2f(h1.y)*x1 + bf2f(h2.y)*x2 + bf2f(h3.y)*x3;
    z2 += bf2f(h0.z)*x0 + bf2f(h1.z)*x1 + bf2f(h2.z)*x2 + bf2f(h3.z)*x3;
    z3 += bf2f(h0.w)*x0 + bf2f(h1.w)*x1 + bf2f(h2.w)*x2 + bf2f(h3.w)*x3;
  }
  for(; i<end; i++){
    int s=cs[i];
    ushort4 h=ch[i];
    float x=bf2f(Abf[(size_t)s*64+lane]);
    z0 += bf2f(h.x)*x; z1 += bf2f(h.y)*x; z2 += bf2f(h.z)*x; z3 += bf2f(h.w)*x;
  }
  size_t base = (size_t)wid*ZS + r*256;
  Zbf[base       + lane] = f2bf(z0);
  Zbf[base + 64  + lane] = f2bf(z1);
  Zbf[base + 128 + lane] = f2bf(z2);
  Zbf[base + 192 + lane] = f2bf(z3);
  size_t fb = (size_t)wid*ZS + 768;
  if(lane==0)
    Zbf[fb + r] = (end>beg) ? (unsigned short)0x3F80 : (unsigned short)0;
  if(r==0 && lane>=3 && lane<32)
    Zbf[fb + lane] = 0;
}

// ---------------- fused MFMA: out = relu([x|Z] @ Wfused + biasfused) --------
// dostats!=0: also write bf16 copy to Abf2 (distinct buffer!) + accumulate stats.
__global__ void __launch_bounds__(256)
k_mfmaZ(const unsigned short* __restrict__ Abf, const unsigned short* __restrict__ Zbf,
        const float* __restrict__ wbufF, float* __restrict__ out,
        unsigned short* __restrict__ Abf2, float* __restrict__ stats, int dostats){
  __shared__ float spart[4][2][64];
  const unsigned short* Wf = (const unsigned short*)wbufF;
  const float* biasF = (const float*)((const char*)wbufF + 110592);
  int t = threadIdx.x, wv = t>>6, lane = t&63, m = lane&15, kq = lane>>4;
  int row = blockIdx.x*64 + wv*16 + m;
  int rc = row < NN ? row : NN-1;
  floatx4 acc0 = {0.f,0.f,0.f,0.f};
  floatx4 acc1 = {0.f,0.f,0.f,0.f};
  floatx4 acc2 = {0.f,0.f,0.f,0.f};
  floatx4 acc3 = {0.f,0.f,0.f,0.f};
  const unsigned short* Arow = Abf + (size_t)rc*64;
  const unsigned short* Zrow = Zbf + (size_t)rc*ZS;
  #pragma unroll
  for(int kb=0; kb<27; kb++){
    short8 a;
    if(kb<2) a = *(const short8*)(Arow + kb*32 + kq*8);
    else     a = *(const short8*)(Zrow + (kb-2)*32 + kq*8);
    int ko = kb*32 + kq*8;
    short8 b0 = *(const short8*)(Wf + (size_t)(0*16+m)*KTOT + ko);
    short8 b1 = *(const short8*)(Wf + (size_t)(1*16+m)*KTOT + ko);
    short8 b2 = *(const short8*)(Wf + (size_t)(2*16+m)*KTOT + ko);
    short8 b3 = *(const short8*)(Wf + (size_t)(3*16+m)*KTOT + ko);
    acc0 = __builtin_amdgcn_mfma_f32_16x16x32_bf16(a, b0, acc0, 0,0,0);
    acc1 = __builtin_amdgcn_mfma_f32_16x16x32_bf16(a, b1, acc1, 0,0,0);
    acc2 = __builtin_amdgcn_mfma_f32_16x16x32_bf16(a, b2, acc2, 0,0,0);
    acc3 = __builtin_amdgcn_mfma_f32_16x16x32_bf16(a, b3, acc3, 0,0,0);
  }
  int orow = blockIdx.x*64 + wv*16 + kq*4;
  #pragma unroll
  for(int ct=0; ct<4; ct++){
    int col = ct*16 + m;
    floatx4 acc = (ct==0)?acc0:(ct==1)?acc1:(ct==2)?acc2:acc3;
    float bb = biasF[col];
    float sv=0.f, qv=0.f;
    #pragma unroll
    for(int ri=0; ri<4; ri++){
      int ro = orow + ri;
      if(ro < NN){
        float v = fmaxf(acc[ri] + bb, 0.f);
        out[(size_t)ro*64 + col] = v;
        if(dostats){
          Abf2[(size_t)ro*64 + col] = f2bf(v);
          sv += v; qv += v*v;
        }
      }
    }
    if(dostats){
      sv += __shfl_xor(sv, 16, 64); qv += __shfl_xor(qv, 16, 64);
      sv += __shfl_xor(sv, 32, 64); qv += __shfl_xor(qv, 32, 64);
      if(kq==0){ spart[wv][0][col]=sv; spart[wv][1][col]=qv; }
    }
  }
  if(dostats){
    __syncthreads();
    if(t<64){
      float s = spart[0][0][t]+spart[1][0][t]+spart[2][0][t]+spart[3][0][t];
      float q = spart[0][1][t]+spart[1][1][t]+spart[2][1][t]+spart[3][1][t];
      atomicAdd(&stats[t], s); atomicAdd(&stats[64+t], q);
    }
  }
}

extern "C" void kernel_launch(void* const* d_in, const int* in_sizes, int n_in,
                              void* d_out, int out_size, void* d_ws, size_t ws_size,
                              hipStream_t stream){
  const float* x      =(const float*)d_in[0];
  const int* src_res  =(const int*)d_in[1];
  const int* dst_res  =(const int*)d_in[2];
  const int* src_seq  =(const int*)d_in[3];
  const int* dst_seq  =(const int*)d_in[4];
  const int* src_knn  =(const int*)d_in[5];
  const int* dst_knn  =(const int*)d_in[6];
  const float* W0 =(const float*)d_in[7];
  const float* al0=(const float*)d_in[8];
  const float* ar0=(const float*)d_in[9];
  const float* b0 =(const float*)d_in[10];
  const float* rW0=(const float*)d_in[11];
  const float* W1 =(const float*)d_in[12];
  const float* al1=(const float*)d_in[13];
  const float* ar1=(const float*)d_in[14];
  const float* b1 =(const float*)d_in[15];
  const float* rW1=(const float*)d_in[16];
  const float* fcW0=(const float*)d_in[17];
  const float* fcb0=(const float*)d_in[18];
  const float* fcW1=(const float*)d_in[19];
  const float* fcb1=(const float*)d_in[20];
  const float* g0 =(const float*)d_in[21];
  const float* be0=(const float*)d_in[22];
  const float* g1 =(const float*)d_in[23];
  const float* be1=(const float*)d_in[24];

  char* ws=(char*)d_ws;
  int*   hist   =(int*)  (ws+0);               // 3*NN ints
  float* stats0 =(float*)(ws+600000);
  float* stats1 =(float*)(ws+600512);
  int*   rowptr =(int*)  (ws+601024);          // 3*RPS ints
  int*   cursor =(int*)  (ws+1201088);
  int*   csr    =(int*)  (ws+1801088);         // 900000 ints
  float* wbuf   =(float*)(ws+5401088);         // ~117 KB
  int*   bsums  =(int*)  (ws+5525344);         // 39 ints
  unsigned short* Abf  =(unsigned short*)(ws+5526528);   // NN*64 bf16 = 6.4MB
  unsigned short* Zbf  =(unsigned short*)(ws+11926528UL);// NN*ZS bf16 = 80MB
  float* xbuf   =(float*)(ws+91926528UL);      // NN*64 f32
  float* EL     =(float*)(ws+104726528UL);     // 3*NN*8 f32
  ushort4* coefh=(ushort4*)(ws+109526528UL);   // 900000 ushort4 = 7.2MB
  unsigned short* Abf2 =(unsigned short*)(ws+123926528UL); // NN*64 bf16 (layer-2 A)

  hipMemsetAsync(ws, 0, 601024, stream);  // hist + both stats buffers

  const int EBLK=(ETOT+255)/256;   // 3516
  k_hist3<<<EBLK,256,0,stream>>>(dst_res,dst_seq,dst_knn,hist);
  k_blocksum<<<3*SNB,256,0,stream>>>(hist,bsums);
  k_scanwrite<<<3*SNB,256,0,stream>>>(hist,bsums,rowptr,cursor);
  k_scatter3<<<EBLK,256,0,stream>>>(src_res,dst_res,src_seq,dst_seq,
                                    src_knn,dst_knn,cursor,csr);

  const int ZBLK=(3*NN*64)/256;  // 37500 (exact)
  // ---- layer 1 ----
  k_bnstats<<<256,256,0,stream>>>(x,stats0,Abf);
  k_prep3<<<59,256,0,stream>>>(stats0,g0,be0,W0,al0,ar0,b0,rW0,fcW0,fcb0,wbuf);
  k_el3<<<3*NBLK,256,0,stream>>>(x,wbuf,EL);
  k_edgecoef3<<<3*NBLK,256,0,stream>>>(EL,rowptr,csr,coefh);
  k_aggzr<<<ZBLK,256,0,stream>>>(Abf,rowptr,csr,coefh,Zbf);
  // layer-1 matmul: writes xbuf f32 + Abf2 bf16 (layer-2 input) + stats1
  k_mfmaZ<<<MBLK,256,0,stream>>>(Abf,Zbf,wbuf,xbuf,Abf2,stats1,1);
  // ---- layer 2 ----
  k_prep3<<<59,256,0,stream>>>(stats1,g1,be1,W1,al1,ar1,b1,rW1,fcW1,fcb1,wbuf);
  k_el3<<<3*NBLK,256,0,stream>>>(xbuf,wbuf,EL);
  k_edgecoef3<<<3*NBLK,256,0,stream>>>(EL,rowptr,csr,coefh);
  k_aggzr<<<ZBLK,256,0,stream>>>(Abf2,rowptr,csr,coefh,Zbf);
  k_mfmaZ<<<MBLK,256,0,stream>>>(Abf2,Zbf,wbuf,(float*)d_out,Abf2,stats0,0);
}